// Round 1
// baseline (31.620 us; speedup 1.0000x reference)
//
#include <hip/hip_runtime.h>

#define BB 32
#define TT 32
#define GT_PER 8
#define DET_PER 24
#define PER 32
#define NN 1024
#define DD 256
#define PADF 260  // padded floats per LDS row (260 % 32 = 4 -> spreads banks a bit)

__global__ __launch_bounds__(256) void frame_kernel(
    const float* __restrict__ x, const float* __restrict__ conf,
    const int* __restrict__ ids, const float* __restrict__ scores,
    const int* __restrict__ tarr, const int* __restrict__ mi,
    float* __restrict__ scene_sum, float* __restrict__ scene_cnt)
{
    __shared__ float sx[PER * PADF];     // 32 nodes x 256 floats (padded)
    __shared__ float ssim[PER * 9];      // sim[r][c], stride 9 (conflict-free)
    __shared__ float sinv[PER];
    __shared__ int   sids[PER], st[PER], smi[PER];
    __shared__ float sconf[PER], sscore[PER];

    const int tid = threadIdx.x;
    const int blk = blockIdx.x;
    const int b = blk / TT;
    const int f = blk % TT;
    const long n0 = (long)b * NN + (long)f * PER;   // first node of this frame

    // ---- stage x tile: 32*256 floats = 2048 float4, 8 per thread, coalesced ----
    const float4* xg = (const float4*)(x + n0 * DD);
    #pragma unroll
    for (int j = 0; j < 8; ++j) {
        int i4 = tid + j * 256;
        int node = i4 >> 6;          // 64 float4 per node
        int k4   = i4 & 63;
        float4 v = xg[i4];
        *(float4*)(&sx[node * PADF + k4 * 4]) = v;
    }
    if (tid < PER) {
        sids[tid]   = ids[n0 + tid];
        st[tid]     = tarr[n0 + tid];
        smi[tid]    = mi[n0 + tid];
        sconf[tid]  = conf[n0 + tid];
        sscore[tid] = scores[n0 + tid];
    }
    __syncthreads();

    // ---- per-node inverse norms: 8 lanes per node ----
    {
        int node = tid >> 3, g = tid & 7;
        float s = 0.f;
        #pragma unroll
        for (int m = 0; m < 8; ++m) {
            int k4 = g + m * 8;
            float4 v = *(const float4*)(&sx[node * PADF + k4 * 4]);
            s += v.x * v.x + v.y * v.y + v.z * v.z + v.w * v.w;
        }
        s += __shfl_xor(s, 1);
        s += __shfl_xor(s, 2);
        s += __shfl_xor(s, 4);
        if (g == 0) sinv[node] = rsqrtf(s);
    }
    __syncthreads();

    // ---- sim[r][c] for r in 0..31 (all nodes), c in 0..7 (gt slots) ----
    {
        int r = tid >> 3, c = tid & 7;
        const float* xr = &sx[r * PADF];
        const float* xc = &sx[c * PADF];
        float s = 0.f;
        #pragma unroll 8
        for (int k4 = 0; k4 < 64; ++k4) {
            float4 a  = *(const float4*)(xr + k4 * 4);
            float4 bb = *(const float4*)(xc + k4 * 4);
            s += a.x * bb.x + a.y * bb.y + a.z * bb.z + a.w * bb.w;
        }
        ssim[r * 9 + c] = 10.f * s * sinv[r] * sinv[c];
    }
    __syncthreads();

    // ---- per-row CE + MSE, frame reduction (wave 0 only) ----
    if (tid < 64) {
        int r = tid;
        float contrib = 0.f;
        int packed = 0;   // valid | det<<8 | gt<<16
        if (r < PER) {
            bool validr = sids[r] >= 0;
            bool detr = validr && (smi[r] != 0);
            bool gtr  = validr && (smi[r] == 0);
            packed = (validr ? 1 : 0) | ((detr ? 1 : 0) << 8) | ((gtr ? 1 : 0) << 16);
            if (detr) {
                float m = -1e30f;
                float tgt = 0.f;
                #pragma unroll
                for (int c = 0; c < GT_PER; ++c) {
                    bool cv = (sids[c] >= 0) && (smi[c] == 0) && (st[c] == st[r]);
                    float s = ssim[r * 9 + c];
                    if (cv) {
                        m = fmaxf(m, s);
                        if (sids[c] == sids[r]) tgt += s;
                    }
                }
                float se = 0.f;
                #pragma unroll
                for (int c = 0; c < GT_PER; ++c) {
                    bool cv = (sids[c] >= 0) && (smi[c] == 0) && (st[c] == st[r]);
                    if (cv) se += expf(ssim[r * 9 + c] - m);
                }
                float lse = m + logf(se);
                float ce = lse - tgt;
                float df = sconf[r] - sscore[r];
                contrib = ce + df * df;
            }
        }
        #pragma unroll
        for (int mask = 1; mask < 64; mask <<= 1) {
            contrib += __shfl_xor(contrib, mask);
            packed  += __shfl_xor(packed, mask);
        }
        if (tid == 0) {
            int vcnt = packed & 0xff;
            int dcnt = (packed >> 8) & 0xff;
            int gcnt = (packed >> 16) & 0xff;
            bool vf = (vcnt > 0) && (dcnt > 0) && (gcnt > 0);
            if (vf) {
                float denom = fmaxf((float)dcnt, 1.f);
                atomicAdd(&scene_sum[b], contrib / denom);
                atomicAdd(&scene_cnt[b], 1.f);
            }
        }
    }
}

__global__ __launch_bounds__(64) void finalize_kernel(
    const float* __restrict__ scene_sum, const float* __restrict__ scene_cnt,
    float* __restrict__ out)
{
    int tid = threadIdx.x;
    float v = 0.f;
    if (tid < BB) {
        float c = scene_cnt[tid];
        v = scene_sum[tid] / fmaxf(c, 1.f);
    }
    #pragma unroll
    for (int mask = 1; mask < 64; mask <<= 1) v += __shfl_xor(v, mask);
    if (tid == 0) out[0] = v / (float)BB;
}

extern "C" void kernel_launch(void* const* d_in, const int* in_sizes, int n_in,
                              void* d_out, int out_size, void* d_ws, size_t ws_size,
                              hipStream_t stream) {
    const float* x      = (const float*)d_in[0];
    const float* conf   = (const float*)d_in[1];
    const int*   ids    = (const int*)d_in[2];
    const float* scores = (const float*)d_in[3];
    const int*   tarr   = (const int*)d_in[4];
    const int*   mi     = (const int*)d_in[5];
    float* out = (float*)d_out;

    float* scene_sum = (float*)d_ws;
    float* scene_cnt = scene_sum + BB;

    hipMemsetAsync(d_ws, 0, 2 * BB * sizeof(float), stream);
    frame_kernel<<<dim3(BB * TT), 256, 0, stream>>>(
        x, conf, ids, scores, tarr, mi, scene_sum, scene_cnt);
    finalize_kernel<<<1, 64, 0, stream>>>(scene_sum, scene_cnt, out);
}

// Round 2
// 30.302 us; speedup vs baseline: 1.0435x; 1.0435x over previous
//
#include <hip/hip_runtime.h>

#define BB 32
#define TT 32
#define GT_PER 8
#define PER 32
#define NN 1024
#define DD 256

__device__ __forceinline__ float dot4(float4 a, float4 b) {
    return a.x * b.x + a.y * b.y + a.z * b.z + a.w * b.w;
}

__global__ __launch_bounds__(256) void frame_kernel(
    const float* __restrict__ x, const float* __restrict__ conf,
    const int* __restrict__ ids, const float* __restrict__ scores,
    const int* __restrict__ tarr, const int* __restrict__ mi,
    float* __restrict__ scene_sum, float* __restrict__ scene_cnt)
{
    __shared__ float sgt[GT_PER * DD];      // 8 KiB: gt rows, linear [8][256]
    __shared__ float sdot[PER * 9];         // raw dots, stride 9 (odd -> conflict-free)
    __shared__ float snorm[PER];
    __shared__ int   sids[PER], smi[PER], st[PER];
    __shared__ float sconf[PER], sscore[PER];

    const int tid = threadIdx.x;
    const int b = blockIdx.x / TT;
    const int f = blockIdx.x % TT;
    const long n0 = (long)b * NN + (long)f * PER;
    const float4* xg4 = (const float4*)(x + n0 * DD);   // 32 rows x 64 float4

    // ---- stage gt rows (rows 0..7 = 512 float4) into LDS, coalesced ----
    {
        float4 v0 = xg4[tid];
        float4 v1 = xg4[tid + 256];
        *(float4*)&sgt[tid * 4]         = v0;
        *(float4*)&sgt[(tid + 256) * 4] = v1;
    }
    if (tid < PER) {
        sids[tid]   = ids[n0 + tid];
        smi[tid]    = mi[n0 + tid];
        st[tid]     = tarr[n0 + tid];
        sconf[tid]  = conf[n0 + tid];
        sscore[tid] = scores[n0 + tid];
    }
    __syncthreads();

    // ---- group (16 lanes) owns rows 2G, 2G+1 in registers; dot vs 8 gt rows ----
    {
        const int G = tid >> 4;        // 0..15
        const int l = tid & 15;        // lane in group
        const int r0 = 2 * G, r1 = r0 + 1;

        float4 a0[4], a1[4];
        #pragma unroll
        for (int j = 0; j < 4; ++j) {
            a0[j] = xg4[r0 * 64 + l + 16 * j];
            a1[j] = xg4[r1 * 64 + l + 16 * j];
        }
        float nrm0 = 0.f, nrm1 = 0.f;
        #pragma unroll
        for (int j = 0; j < 4; ++j) {
            nrm0 += dot4(a0[j], a0[j]);
            nrm1 += dot4(a1[j], a1[j]);
        }
        float d0[GT_PER], d1[GT_PER];
        #pragma unroll
        for (int c = 0; c < GT_PER; ++c) {
            float s0 = 0.f, s1 = 0.f;
            #pragma unroll
            for (int j = 0; j < 4; ++j) {
                float4 bv = *(const float4*)&sgt[(c * 64 + l + 16 * j) * 4];
                s0 += dot4(a0[j], bv);
                s1 += dot4(a1[j], bv);
            }
            d0[c] = s0; d1[c] = s1;
        }
        // 16-lane butterfly reduce (stays within group for masks 1,2,4,8)
        #pragma unroll
        for (int m = 1; m < 16; m <<= 1) {
            nrm0 += __shfl_xor(nrm0, m);
            nrm1 += __shfl_xor(nrm1, m);
            #pragma unroll
            for (int c = 0; c < GT_PER; ++c) {
                d0[c] += __shfl_xor(d0[c], m);
                d1[c] += __shfl_xor(d1[c], m);
            }
        }
        if (l == 0) {
            snorm[r0] = nrm0;
            snorm[r1] = nrm1;
            #pragma unroll
            for (int c = 0; c < GT_PER; ++c) {
                sdot[r0 * 9 + c] = d0[c];
                sdot[r1 * 9 + c] = d1[c];
            }
        }
    }
    __syncthreads();

    // ---- per-row CE + MSE, frame reduction (wave 0 only) ----
    if (tid < 64) {
        int r = tid;
        float contrib = 0.f;
        int packed = 0;   // valid | det<<8 | gt<<16
        if (r < PER) {
            bool validr = sids[r] >= 0;
            bool detr = validr && (smi[r] != 0);
            bool gtr  = validr && (smi[r] == 0);
            packed = (validr ? 1 : 0) | ((detr ? 1 : 0) << 8) | ((gtr ? 1 : 0) << 16);
            if (detr) {
                float sinr = rsqrtf(snorm[r]);
                float m = -1e30f;
                float tgt = 0.f;
                float simv[GT_PER];
                int cvmask = 0;
                #pragma unroll
                for (int c = 0; c < GT_PER; ++c) {
                    bool cv = (sids[c] >= 0) && (smi[c] == 0) && (st[c] == st[r]);
                    float s = 10.f * sdot[r * 9 + c] * sinr * rsqrtf(snorm[c]);
                    simv[c] = s;
                    if (cv) {
                        cvmask |= (1 << c);
                        m = fmaxf(m, s);
                        if (sids[c] == sids[r]) tgt += s;
                    }
                }
                float se = 0.f;
                #pragma unroll
                for (int c = 0; c < GT_PER; ++c) {
                    if (cvmask & (1 << c)) se += expf(simv[c] - m);
                }
                float lse = m + logf(se);
                float ce = lse - tgt;
                float df = sconf[r] - sscore[r];
                contrib = ce + df * df;
            }
        }
        #pragma unroll
        for (int mask = 1; mask < 64; mask <<= 1) {
            contrib += __shfl_xor(contrib, mask);
            packed  += __shfl_xor(packed, mask);
        }
        if (tid == 0) {
            int vcnt = packed & 0xff;
            int dcnt = (packed >> 8) & 0xff;
            int gcnt = (packed >> 16) & 0xff;
            bool vf = (vcnt > 0) && (dcnt > 0) && (gcnt > 0);
            if (vf) {
                float denom = fmaxf((float)dcnt, 1.f);
                atomicAdd(&scene_sum[b], contrib / denom);
                atomicAdd(&scene_cnt[b], 1.f);
            }
        }
    }
}

__global__ __launch_bounds__(64) void finalize_kernel(
    const float* __restrict__ scene_sum, const float* __restrict__ scene_cnt,
    float* __restrict__ out)
{
    int tid = threadIdx.x;
    float v = 0.f;
    if (tid < BB) {
        float c = scene_cnt[tid];
        v = scene_sum[tid] / fmaxf(c, 1.f);
    }
    #pragma unroll
    for (int mask = 1; mask < 64; mask <<= 1) v += __shfl_xor(v, mask);
    if (tid == 0) out[0] = v / (float)BB;
}

extern "C" void kernel_launch(void* const* d_in, const int* in_sizes, int n_in,
                              void* d_out, int out_size, void* d_ws, size_t ws_size,
                              hipStream_t stream) {
    const float* x      = (const float*)d_in[0];
    const float* conf   = (const float*)d_in[1];
    const int*   ids    = (const int*)d_in[2];
    const float* scores = (const float*)d_in[3];
    const int*   tarr   = (const int*)d_in[4];
    const int*   mi     = (const int*)d_in[5];
    float* out = (float*)d_out;

    float* scene_sum = (float*)d_ws;
    float* scene_cnt = scene_sum + BB;

    hipMemsetAsync(d_ws, 0, 2 * BB * sizeof(float), stream);
    frame_kernel<<<dim3(BB * TT), 256, 0, stream>>>(
        x, conf, ids, scores, tarr, mi, scene_sum, scene_cnt);
    finalize_kernel<<<1, 64, 0, stream>>>(scene_sum, scene_cnt, out);
}

// Round 3
// 16.683 us; speedup vs baseline: 1.8954x; 1.8163x over previous
//
#include <hip/hip_runtime.h>

#define BB 32
#define TT 32
#define GT_PER 8
#define PER 32
#define NN 1024
#define DD 256
#define NFRAMES (BB * TT)   // 1024

__device__ __forceinline__ float dot4(float4 a, float4 b) {
    return a.x * b.x + a.y * b.y + a.z * b.z + a.w * b.w;
}

// One block per (scene, frame). Writes (frame_loss, frame_valid) to ws.
__global__ __launch_bounds__(256) void frame_kernel(
    const float* __restrict__ x, const float* __restrict__ conf,
    const int* __restrict__ ids, const float* __restrict__ scores,
    const int* __restrict__ tarr, const int* __restrict__ mi,
    float* __restrict__ frame_loss, float* __restrict__ frame_valid)
{
    __shared__ float sgt[GT_PER * DD];      // 8 KiB: gt rows [8][256] linear
    __shared__ float sdot[PER * 9];         // raw dots, stride 9 (odd -> conflict-free)
    __shared__ float snorm[PER];
    __shared__ int   sids[PER], smi[PER], st[PER];
    __shared__ float sconf[PER], sscore[PER];

    const int tid = threadIdx.x;
    const int b = blockIdx.x / TT;
    const int f = blockIdx.x % TT;
    const long n0 = (long)b * NN + (long)f * PER;
    const float4* xg4 = (const float4*)(x + n0 * DD);   // 32 rows x 64 float4

    const int G = tid >> 4;        // 0..15
    const int l = tid & 15;        // lane in group
    const int r0 = 2 * G, r1 = r0 + 1;

    // ---- each group loads its 2 rows into registers (sole global read of x) ----
    float4 a0[4], a1[4];
    #pragma unroll
    for (int j = 0; j < 4; ++j) {
        a0[j] = xg4[r0 * 64 + l + 16 * j];
        a1[j] = xg4[r1 * 64 + l + 16 * j];
    }
    // groups 0..3 own rows 0..7 (the GT rows): publish them to LDS from registers
    if (G < 4) {
        #pragma unroll
        for (int j = 0; j < 4; ++j) {
            *(float4*)&sgt[(r0 * 64 + l + 16 * j) * 4] = a0[j];
            *(float4*)&sgt[(r1 * 64 + l + 16 * j) * 4] = a1[j];
        }
    }
    if (tid < PER) {
        sids[tid]   = ids[n0 + tid];
        smi[tid]    = mi[n0 + tid];
        st[tid]     = tarr[n0 + tid];
        sconf[tid]  = conf[n0 + tid];
        sscore[tid] = scores[n0 + tid];
    }
    __syncthreads();

    // ---- dots of own 2 rows vs 8 gt rows + own norms ----
    {
        float nrm0 = 0.f, nrm1 = 0.f;
        #pragma unroll
        for (int j = 0; j < 4; ++j) {
            nrm0 += dot4(a0[j], a0[j]);
            nrm1 += dot4(a1[j], a1[j]);
        }
        float d0[GT_PER], d1[GT_PER];
        #pragma unroll
        for (int c = 0; c < GT_PER; ++c) {
            float s0 = 0.f, s1 = 0.f;
            #pragma unroll
            for (int j = 0; j < 4; ++j) {
                float4 bv = *(const float4*)&sgt[(c * 64 + l + 16 * j) * 4];
                s0 += dot4(a0[j], bv);
                s1 += dot4(a1[j], bv);
            }
            d0[c] = s0; d1[c] = s1;
        }
        // 16-lane butterfly reduce (masks 1,2,4,8 stay within the group)
        #pragma unroll
        for (int m = 1; m < 16; m <<= 1) {
            nrm0 += __shfl_xor(nrm0, m);
            nrm1 += __shfl_xor(nrm1, m);
            #pragma unroll
            for (int c = 0; c < GT_PER; ++c) {
                d0[c] += __shfl_xor(d0[c], m);
                d1[c] += __shfl_xor(d1[c], m);
            }
        }
        if (l == 0) {
            snorm[r0] = nrm0;
            snorm[r1] = nrm1;
            #pragma unroll
            for (int c = 0; c < GT_PER; ++c) {
                sdot[r0 * 9 + c] = d0[c];
                sdot[r1 * 9 + c] = d1[c];
            }
        }
    }
    __syncthreads();

    // ---- per-row CE + MSE, frame reduction (wave 0 only) ----
    if (tid < 64) {
        int r = tid;
        float contrib = 0.f;
        int packed = 0;   // valid | det<<8 | gt<<16
        if (r < PER) {
            bool validr = sids[r] >= 0;
            bool detr = validr && (smi[r] != 0);
            bool gtr  = validr && (smi[r] == 0);
            packed = (validr ? 1 : 0) | ((detr ? 1 : 0) << 8) | ((gtr ? 1 : 0) << 16);
            if (detr) {
                float sinr = rsqrtf(snorm[r]);
                float m = -1e30f;
                float tgt = 0.f;
                float simv[GT_PER];
                int cvmask = 0;
                #pragma unroll
                for (int c = 0; c < GT_PER; ++c) {
                    bool cv = (sids[c] >= 0) && (smi[c] == 0) && (st[c] == st[r]);
                    float s = 10.f * sdot[r * 9 + c] * sinr * rsqrtf(snorm[c]);
                    simv[c] = s;
                    if (cv) {
                        cvmask |= (1 << c);
                        m = fmaxf(m, s);
                        if (sids[c] == sids[r]) tgt += s;
                    }
                }
                float se = 0.f;
                #pragma unroll
                for (int c = 0; c < GT_PER; ++c) {
                    if (cvmask & (1 << c)) se += expf(simv[c] - m);
                }
                float lse = m + logf(se);
                float ce = lse - tgt;
                float df = sconf[r] - sscore[r];
                contrib = ce + df * df;
            }
        }
        #pragma unroll
        for (int mask = 1; mask < 64; mask <<= 1) {
            contrib += __shfl_xor(contrib, mask);
            packed  += __shfl_xor(packed, mask);
        }
        if (tid == 0) {
            int vcnt = packed & 0xff;
            int dcnt = (packed >> 8) & 0xff;
            int gcnt = (packed >> 16) & 0xff;
            bool vf = (vcnt > 0) && (dcnt > 0) && (gcnt > 0);
            float denom = fmaxf((float)dcnt, 1.f);
            // unconditional write: no memset needed, no atomics
            frame_loss[blockIdx.x]  = vf ? (contrib / denom) : 0.f;
            frame_valid[blockIdx.x] = vf ? 1.f : 0.f;
        }
    }
}

// One block, 1024 threads: thread = scene*32 + frame.
__global__ __launch_bounds__(1024) void finalize_kernel(
    const float* __restrict__ frame_loss, const float* __restrict__ frame_valid,
    float* __restrict__ out)
{
    __shared__ float sl[BB];
    const int tid = threadIdx.x;           // 0..1023
    float fl = frame_loss[tid];
    float fv = frame_valid[tid];
    // reduce over 32 frames of one scene (masks 1..16 stay in 32-lane half-wave)
    #pragma unroll
    for (int m = 1; m < 32; m <<= 1) {
        fl += __shfl_xor(fl, m);
        fv += __shfl_xor(fv, m);
    }
    if ((tid & 31) == 0) sl[tid >> 5] = fl / fmaxf(fv, 1.f);
    __syncthreads();
    if (tid < 64) {
        float v = (tid < BB) ? sl[tid] : 0.f;
        #pragma unroll
        for (int m = 1; m < 64; m <<= 1) v += __shfl_xor(v, m);
        if (tid == 0) out[0] = v / (float)BB;
    }
}

extern "C" void kernel_launch(void* const* d_in, const int* in_sizes, int n_in,
                              void* d_out, int out_size, void* d_ws, size_t ws_size,
                              hipStream_t stream) {
    const float* x      = (const float*)d_in[0];
    const float* conf   = (const float*)d_in[1];
    const int*   ids    = (const int*)d_in[2];
    const float* scores = (const float*)d_in[3];
    const int*   tarr   = (const int*)d_in[4];
    const int*   mi     = (const int*)d_in[5];
    float* out = (float*)d_out;

    float* frame_loss  = (float*)d_ws;            // [1024]
    float* frame_valid = frame_loss + NFRAMES;    // [1024]

    frame_kernel<<<dim3(NFRAMES), 256, 0, stream>>>(
        x, conf, ids, scores, tarr, mi, frame_loss, frame_valid);
    finalize_kernel<<<1, 1024, 0, stream>>>(frame_loss, frame_valid, out);
}